// Round 19
// baseline (130.725 us; speedup 1.0000x reference)
//
#include <hip/hip_runtime.h>

// LSTM-cell (h0=c0=0) + Linear, re-fused.  out = Lin(h(x @ W_ih^T + b)).
// x: [65536,1024] f32 -> out: [65536,1024] f32.
// R19 = R18 with the compile error fixed (guard fn removed; b_lin passed
// directly). Fusion rationale unchanged:
//   R16 lesson: NT loads HURT (114->121; L3 serves part of x) => x cached.
//   NT stores WIN (R15: +38% on lin) => out stores NT.
//   Same-stream kernels serialize => gates' pure-read 57us and lin's
//   pure-write 57us never overlap; fused, the 4 co-resident blocks/CU drift
//   out of phase => chip-wide mixed read+write streams. Kills g_h (-16MB).
// Phase 1 + nonlin: verbatim R15 gates (h stays in LDS). Phase 2: R10's
// operand-swap lin with NONTEMPORAL float4 stores + ct rotation.

typedef _Float16 f16;
typedef f16 f16x8 __attribute__((ext_vector_type(8)));
typedef float f32x4 __attribute__((ext_vector_type(4)));

#define W1S_ELEMS (32 * 10 * 64)   // f16x8 units: [ks32][gt][lane]
#define W2S_ELEMS (64 * 2 * 64)    // f16x8 units: [ct][ks2][lane]

__device__ f16x8 g_w1s[W1S_ELEMS];
__device__ f16x8 g_w2s[W2S_ELEMS];
__device__ float g_bias[160];

__device__ __forceinline__ int pack_map(int j) {
    return (j < 50) ? j : (j < 150) ? (j + 50) : -1;   // skip dead f-gate rows
}

__global__ __launch_bounds__(256) void prep_kernel(
    const float* __restrict__ W_ih, const float* __restrict__ b_ih,
    const float* __restrict__ b_hh, const float* __restrict__ W_lin)
{
    int idx = blockIdx.x * 256 + threadIdx.x;
    if (idx < W1S_ELEMS) {
        int lane = idx & 63, rest = idx >> 6;
        int gt = rest % 10, ks = rest / 10;
        int prow = gt * 16 + (lane & 15);
        int oj = pack_map(prow);
        int k0 = ks * 32 + ((lane >> 4) << 3);
        f16x8 v;
        #pragma unroll
        for (int j = 0; j < 8; ++j)
            v[j] = (f16)((oj >= 0) ? W_ih[oj * 1024 + k0 + j] : 0.f);
        g_w1s[idx] = v;
    } else if (idx < W1S_ELEMS + W2S_ELEMS) {
        int i2 = idx - W1S_ELEMS;
        int lane = i2 & 63, rest = i2 >> 6;
        int ks = rest & 1, ct = rest >> 1;
        int ocol = ct * 16 + (lane & 15);
        int k0 = ks * 32 + ((lane >> 4) << 3);
        f16x8 v;
        #pragma unroll
        for (int j = 0; j < 8; ++j) {
            int k = k0 + j;
            v[j] = (f16)((k < 50) ? W_lin[ocol * 50 + k] : 0.f);
        }
        g_w2s[i2] = v;
    } else if (idx < W1S_ELEMS + W2S_ELEMS + 160) {
        int i3 = idx - (W1S_ELEMS + W2S_ELEMS);
        int oj = pack_map(i3);
        g_bias[i3] = (oj >= 0) ? (b_ih[oj] + b_hh[oj]) : 0.f;
    }
}

// rotation swizzle for the f32 gate buffer (<=2-way banks both sides)
__device__ __forceinline__ int gaddr(int row, int col) {
    int c = col + ((row & 15) << 2);
    if (c >= 160) c -= 160;
    return row * 160 + c;
}

__device__ __forceinline__ float fast_tanh(float v) {
    float t = __expf(-2.f * v);
    return (1.f - t) / (1.f + t);
}

#define GLOAD16(gp, lp) __builtin_amdgcn_global_load_lds( \
    (const __attribute__((address_space(1))) void*)(gp),  \
    (__attribute__((address_space(3))) void*)(lp), 16, 0, 0)

// ---- fused: x -> h (LDS) -> out.  64 rows/block, grid 1024, 4 blocks/CU ----
__global__ __launch_bounds__(256, 4) void lstm_fused(
    const float* __restrict__ x, const float* __restrict__ blin,
    float* __restrict__ out)
{
    __shared__ __align__(16) char smem[40960];
    float* gs = (float*)smem;
    f16*   hs = (f16*)smem;

    const int tid  = threadIdx.x;
    const int lane = tid & 63;
    const int wv   = tid >> 6;
    const int lcol = lane & 15;
    const int l4   = lane >> 4;
    const long row0 = (long)blockIdx.x * 64;
    const int wrow = wv * 16;

    const int bid   = blockIdx.x;
    const int koff  = (bid * 5 + (bid >> 8) * 8) & 31;
    const int ctoff = ((bid * 11 + (bid >> 8) * 16) & 63) + wv * 16;

    const int wt0 = (wv < 2) ? wv * 3 : 6 + (wv - 2) * 2;
    const int nw  = (wv < 2) ? 3 : 2;

    const int sw = ((lane & 7) ^ (lane >> 3)) << 2;
    const float* xsrc0 = x + (row0 + (2 * wv) * 8 + (lane >> 3)) * 1024 + sw;
    const float* xsrc1 = x + (row0 + (2 * wv + 1) * 8 + (lane >> 3)) * 1024 + sw;

    char* xs0 = smem + (2 * wv) * 1024;
    char* xs1 = smem + (2 * wv + 1) * 1024;

    #define STAGE(c, par) do {                                                 \
        const int c_ = (c);                                                    \
        const int p_ = (par);                                                  \
        GLOAD16(xsrc0 + c_ * 32, xs0 + p_ * 8192);                             \
        GLOAD16(xsrc1 + c_ * 32, xs1 + p_ * 8192);                             \
        _Pragma("unroll")                                                      \
        for (int wti = 0; wti < 3; ++wti)                                      \
            if (wti < nw)                                                      \
                GLOAD16((const f16x8*)g_w1s + c_ * 640 + (wt0 + wti) * 64 + lane, \
                        smem + 16384 + p_ * 10240 + (wt0 + wti) * 1024);       \
    } while (0)

    f32x4 acc[10];
    #pragma unroll
    for (int g = 0; g < 10; ++g) acc[g] = (f32x4){0.f, 0.f, 0.f, 0.f};

    STAGE(koff, 0);
    STAGE((koff + 1) & 31, 1);

    const int abyte = (wrow + lcol) * 128;
    const int au0 = ((2 * l4 + 0) ^ (lcol & 7)) << 4;
    const int au1 = ((2 * l4 + 1) ^ (lcol & 7)) << 4;

    for (int t = 0; t < 32; ++t) {
        if (t == 31)       asm volatile("s_waitcnt vmcnt(0)" ::: "memory");
        else if (wv < 2)   asm volatile("s_waitcnt vmcnt(5)" ::: "memory");
        else               asm volatile("s_waitcnt vmcnt(4)" ::: "memory");
        __builtin_amdgcn_sched_barrier(0);
        __builtin_amdgcn_s_barrier();

        const int par = t & 1;
        const char* ab = smem + par * 8192 + abyte;
        float4 qa = *(const float4*)(ab + au0);
        float4 qb = *(const float4*)(ab + au1);
        f16x8 af = { (f16)qa.x, (f16)qa.y, (f16)qa.z, (f16)qa.w,
                     (f16)qb.x, (f16)qb.y, (f16)qb.z, (f16)qb.w };
        const f16x8* wb = (const f16x8*)(smem + 16384 + par * 10240) + lane;
        #pragma unroll
        for (int g = 0; g < 10; ++g) {
            f16x8 bf = wb[g * 64];
            acc[g] = __builtin_amdgcn_mfma_f32_16x16x32_f16(af, bf, acc[g], 0, 0, 0);
        }

        asm volatile("s_waitcnt lgkmcnt(0)" ::: "memory");
        __builtin_amdgcn_sched_barrier(0);
        __builtin_amdgcn_s_barrier();
        if (t < 30) STAGE((t + 2 + koff) & 31, par);
    }

    // gates(+bias) -> swizzled LDS exchange
    #pragma unroll
    for (int g = 0; g < 10; ++g) {
        float bb = g_bias[g * 16 + lcol];
        #pragma unroll
        for (int r = 0; r < 4; ++r)
            gs[gaddr(wrow + l4 * 4 + r, g * 16 + lcol)] = acc[g][r] + bb;
    }
    __syncthreads();

    // nonlinearity -> h regs
    const int nrow = tid >> 2, sub = tid & 3;
    const int c0 = sub * 13;
    float hreg[13];
    #pragma unroll
    for (int j = 0; j < 13; ++j) {
        int c = c0 + j;
        float hv = 0.f;
        if (c < 50) {
            float iv = gs[gaddr(nrow, c)];
            float gv = gs[gaddr(nrow, 50 + c)];
            float ov = gs[gaddr(nrow, 100 + c)];
            float cv = fast_tanh(gv) / (1.f + __expf(-iv));
            hv = fast_tanh(cv) / (1.f + __expf(-ov));
        }
        hreg[j] = hv;
    }
    __syncthreads();

    // h -> LDS [64][72] f16 (overlays gs)
    #pragma unroll
    for (int j = 0; j < 13; ++j)
        hs[nrow * 72 + c0 + j] = (f16)hreg[j];
    if (sub == 3) {
        #pragma unroll
        for (int c = 52; c < 64; ++c) hs[nrow * 72 + c] = (f16)0.f;
    }
    __syncthreads();

    // ---- phase 2: out = h @ W2^T + b_lin; operand swap, NONTEMPORAL stores --
    const int hrow = wrow + lcol;
    f16x8 bh0 = *(const f16x8*)(hs + hrow * 72 + l4 * 8);
    f16x8 bh1 = *(const f16x8*)(hs + hrow * 72 + 32 + l4 * 8);
    float* orow = out + (row0 + hrow) * 1024;

    #pragma unroll 4
    for (int t2 = 0; t2 < 64; ++t2) {
        int ct = (t2 + ctoff) & 63;
        float4 bl = *(const float4*)(blin + ct * 16 + l4 * 4);
        f32x4 o = { bl.x, bl.y, bl.z, bl.w };
        const f16x8* w2b = g_w2s + ct * 128 + lane;
        o = __builtin_amdgcn_mfma_f32_16x16x32_f16(w2b[0],  bh0, o, 0, 0, 0);
        o = __builtin_amdgcn_mfma_f32_16x16x32_f16(w2b[64], bh1, o, 0, 0, 0);
        __builtin_nontemporal_store(o, (f32x4*)(orow + ct * 16 + l4 * 4));
    }
}

extern "C" void kernel_launch(void* const* d_in, const int* in_sizes, int n_in,
                              void* d_out, int out_size, void* d_ws, size_t ws_size,
                              hipStream_t stream) {
    const float* x     = (const float*)d_in[0];
    const float* W_ih  = (const float*)d_in[1];
    // d_in[2] = W_hh — provably unused (h_prev = 0)
    const float* b_ih  = (const float*)d_in[3];
    const float* b_hh  = (const float*)d_in[4];
    const float* W_lin = (const float*)d_in[5];
    const float* b_lin = (const float*)d_in[6];
    float* out = (float*)d_out;

    int prep_total = W1S_ELEMS + W2S_ELEMS + 160;
    prep_kernel<<<(prep_total + 255) / 256, 256, 0, stream>>>(
        W_ih, b_ih, b_hh, W_lin);

    lstm_fused<<<1024, 256, 0, stream>>>(x, b_lin, out);
}